// Round 22
// baseline (347.685 us; speedup 1.0000x reference)
//
#include <hip/hip_runtime.h>
#include <math.h>

typedef _Float16 f16;
typedef _Float16 f16x4 __attribute__((ext_vector_type(4)));
typedef _Float16 f16x8 __attribute__((ext_vector_type(8)));
typedef float    f32x4 __attribute__((ext_vector_type(4)));
typedef float    f32x16 __attribute__((ext_vector_type(16)));
typedef unsigned int u32;
typedef unsigned long long u64;

#define NHEADS 128
#define KLEN   8192
#define DDIM   128
#define SDIM   256
#define NROWS  (NHEADS * KLEN)       // 1,048,576 k-rows
#define SCALE  1.2533141373155003f   // sqrt(pi/2)
#define TAU    2e-5f                 // suspect threshold (validated rounds 3/7/9)

// ---- workspace layout ----
// [0, 1MiB)            : qs16 f16 [128 heads][16 q][256 s]
// [1MiB, +64KiB)       : Gfh  f16 32x32-fragment-ordered hi  [w8][kc8][lane64][8]
// [+64K, +128K)        : Gfl  f16 32x32-fragment-ordered lo*4096
// [+128K, +256K)       : Gt   f32 [256 s][128 d]  (exact, transposed; fixup)
// [2MiB, 2MiB+32MiB)   : packed sign bits, u32[1M rows][8]
// suspect MASK (u32[1M rows][8], 32MB) lives in d_out (dead until est).
#define QS_OFF     0
#define GFH_OFF    (1u << 20)
#define GFL_OFF    ((1u << 20) + (64u << 10))
#define GT_OFF     ((1u << 20) + (128u << 10))
#define PACKED_OFF (2u << 20)

// ------------------------------------------------------------------
// Sequential f32 dot, d-ascending, single-rounding FMA per step —
// bitwise-matches the numpy reference path (validated round 3).
__device__ __forceinline__ float seq_dot_np(const float* __restrict__ a,
                                            const float* __restrict__ gcol) {
  float acc = 0.0f;
  #pragma unroll 8
  for (int d = 0; d < DDIM; ++d)
    acc = __builtin_fmaf(a[d], gcol[d], acc);
  return acc;
}

// ------------------------------------------------------------------
// prep: q_sketch = q @ G  (f32 accumulate, store f16)
__global__ void prep_qs_kernel(const float* __restrict__ q,
                               const float* __restrict__ G,
                               f16* __restrict__ qs16) {
  int idx = blockIdx.x * 256 + threadIdx.x;      // 524288
  int s  = idx & 255;
  int hq = idx >> 8;
  const float* qr = q + (size_t)hq * DDIM;
  float acc = 0.f;
  #pragma unroll 8
  for (int d = 0; d < DDIM; ++d) acc += qr[d] * G[d * SDIM + s];
  qs16[idx] = (f16)acc;
}

// prep: G -> 32x32x16-fragment-ordered f16 hi/lo + f32 transposed copy.
// A-frag for strip w, K-chunk kc: lane&31 -> s = w*32+(lane&31),
// kk = 8*(lane>>5)+j -> d = kc*16 + (lane>>5)*8 + j.
__global__ void prep_g_kernel(const float* __restrict__ G,
                              f16* __restrict__ gfh, f16* __restrict__ gfl,
                              float* __restrict__ gt) {
  int t = blockIdx.x * 256 + threadIdx.x;        // 4096 threads
  int w    = t >> 9;                             // strip 0..7
  int kc   = (t >> 6) & 7;                       // K-chunk 0..7
  int lane = t & 63;
  int s  = w * 32 + (lane & 31);
  int d0 = kc * 16 + (lane >> 5) * 8;
  f16x8 hh, ll;
  #pragma unroll
  for (int j = 0; j < 8; ++j) {
    float g = G[(size_t)(d0 + j) * SDIM + s];
    f16 h = (f16)g;
    hh[j] = h;
    ll[j] = (f16)((g - (float)h) * 4096.0f);
    gt[(size_t)s * DDIM + d0 + j] = g;
  }
  *(f16x8*)(gfh + (size_t)t * 8) = hh;
  *(f16x8*)(gfl + (size_t)t * 8) = ll;
}

// ------------------------------------------------------------------
// Pass A (G-STATIONARY, 32x32x16 MFMA): each wave holds its 32-s strip
// as the A-operand (8 kc x 4 VGPR hi + lo); k streams through one 16KB
// LDS tile of 32 rows as the B-operand. 24 fat MFMA per tile (3 chains
// x 8 kc) = half the instruction count and half the barriers of the
// 16x16 version at 25% better FLOP/cycle. R15's 2-barrier schedule.
// C layout (guide m74/m101): col=lane&31 (k-row), row=(reg&3)+8*(reg>>2)
// +4*(lane>>5) (s_local). grid 4096, 8 tiles of 32 rows per block.
__launch_bounds__(512, 1)
__global__ void proj_sign_kernel(const float* __restrict__ kmat,
                                 const f16* __restrict__ gfh,
                                 const f16* __restrict__ gfl,
                                 u32* __restrict__ packed,
                                 u32* __restrict__ smask) {
  __shared__ __align__(16) f16 lds[2][8][64][8];   // [hilo][kc][lane][8] = 16KB

  const int tid  = threadIdx.x;
  const int lane = tid & 63;
  const int w    = tid >> 6;                     // wave 0..7 = s-strip
  const int l5 = lane >> 5;                      // lane half
  const size_t rowbase = (size_t)blockIdx.x * 256;

  // ---- G fragments (stationary A-operand) for strip [w*32, w*32+32) ----
  f16x8 Gh[8], Gl[8];
  #pragma unroll
  for (int kc = 0; kc < 8; ++kc) {
    size_t o = ((size_t)(w * 8 + kc) * 64 + lane) * 8;
    Gh[kc] = *(const f16x8*)(gfh + o);
    Gl[kc] = *(const f16x8*)(gfl + o);
  }

  // ---- staging indices: thread -> rows (srl, srl+16), one d-quad ----
  const int srl = tid >> 5;                      // 0..15
  const int sd0 = (tid & 31) * 4;                // d offset 0..124
  const int skc = sd0 >> 4;                      // K-chunk 0..7
  const int slot = ((sd0 >> 3) & 1) * 32;        // lane-half base
  const int sj0 = sd0 & 7;                       // 0 or 4
  const float* kp0 = kmat + (rowbase + srl) * DDIM + sd0;

  float4 rv0 = *(const float4*)kp0;
  float4 rv1 = *(const float4*)(kp0 + (size_t)16 * DDIM);

  for (int t = 0; t < 8; ++t) {                  // 8 tiles of 32 rows
    // convert this tile's two quads and write to LDS fragment slots
    {
      f16 h;
      f16x4 h4, l4;
      h = (f16)rv0.x; h4[0] = h; l4[0] = (f16)((rv0.x - (float)h) * 4096.0f);
      h = (f16)rv0.y; h4[1] = h; l4[1] = (f16)((rv0.y - (float)h) * 4096.0f);
      h = (f16)rv0.z; h4[2] = h; l4[2] = (f16)((rv0.z - (float)h) * 4096.0f);
      h = (f16)rv0.w; h4[3] = h; l4[3] = (f16)((rv0.w - (float)h) * 4096.0f);
      *(f16x4*)&lds[0][skc][slot + srl][sj0] = h4;
      *(f16x4*)&lds[1][skc][slot + srl][sj0] = l4;
      h = (f16)rv1.x; h4[0] = h; l4[0] = (f16)((rv1.x - (float)h) * 4096.0f);
      h = (f16)rv1.y; h4[1] = h; l4[1] = (f16)((rv1.y - (float)h) * 4096.0f);
      h = (f16)rv1.z; h4[2] = h; l4[2] = (f16)((rv1.z - (float)h) * 4096.0f);
      h = (f16)rv1.w; h4[3] = h; l4[3] = (f16)((rv1.w - (float)h) * 4096.0f);
      *(f16x4*)&lds[0][skc][slot + srl + 16][sj0] = h4;
      *(f16x4*)&lds[1][skc][slot + srl + 16][sj0] = l4;
    }
    // prefetch next tile early (latency hides under compute below)
    float4 rn0, rn1;
    if (t < 7) {
      const float* np_ = kp0 + (size_t)(t + 1) * 32 * DDIM;
      rn0 = *(const float4*)np_;
      rn1 = *(const float4*)(np_ + (size_t)16 * DDIM);
    }
    __syncthreads();

    // ---- compute: 24 MFMA (3 chains x 8 kc), 32x32x16 ----
    f32x16 ch = {0,0,0,0,0,0,0,0,0,0,0,0,0,0,0,0};
    f32x16 ca = {0,0,0,0,0,0,0,0,0,0,0,0,0,0,0,0};
    f32x16 cb = {0,0,0,0,0,0,0,0,0,0,0,0,0,0,0,0};
    #pragma unroll
    for (int kc = 0; kc < 8; ++kc) {
      f16x8 Bh = *(const f16x8*)&lds[0][kc][lane][0];
      f16x8 Bl = *(const f16x8*)&lds[1][kc][lane][0];
      ch = __builtin_amdgcn_mfma_f32_32x32x16_f16(Gh[kc], Bh, ch, 0, 0, 0);
      ca = __builtin_amdgcn_mfma_f32_32x32x16_f16(Gh[kc], Bl, ca, 0, 0, 0);
      cb = __builtin_amdgcn_mfma_f32_32x32x16_f16(Gl[kc], Bh, cb, 0, 0, 0);
    }
    float p[16];
    #pragma unroll
    for (int r = 0; r < 16; ++r)
      p[r] = ch[r] + (ca[r] + cb[r]) * 2.44140625e-4f;   // 1/4096

    // ---- per-lane bit build: lane owns k-row (lane&31), 16 s-bits ----
    u32 pbits = 0, sbits = 0;
    #pragma unroll
    for (int r = 0; r < 16; ++r) {
      int srow = (r & 3) + 8 * (r >> 2) + 4 * l5;
      if (p[r] > 0.0f) pbits |= (1u << srow);
    }
    float mn = __builtin_fabsf(p[0]);
    #pragma unroll
    for (int r = 1; r < 16; ++r)
      mn = fminf(mn, __builtin_fabsf(p[r]));
    if (__any(mn < TAU ? 1 : 0)) {
      #pragma unroll
      for (int r = 0; r < 16; ++r) {
        int srow = (r & 3) + 8 * (r >> 2) + 4 * l5;
        if (__builtin_fabsf(p[r]) < TAU) sbits |= (1u << srow);
      }
    }
    // combine lane halves (L, L+32) -> full 32-bit word per k-row
    pbits |= __shfl_xor(pbits, 32);
    sbits |= __shfl_xor(sbits, 32);
    if (lane < 32) {
      size_t row = rowbase + (size_t)t * 32 + lane;
      packed[row * 8 + w] = pbits;
      smask [row * 8 + w] = sbits;
    }
    __syncthreads();                             // before overwriting LDS
    if (t < 7) { rv0 = rn0; rv1 = rn1; }
  }
}

// ------------------------------------------------------------------
// Pass B: one thread per k-row; ~6K suspects total -> mask-scan bound.
__global__ void fixup_kernel(const float* __restrict__ kmat,
                             const float* __restrict__ gt,
                             u32* __restrict__ packed,
                             const u32* __restrict__ smask) {
  int row = blockIdx.x * 256 + threadIdx.x;
  if (row >= NROWS) return;
  const u32* mp = smask + (size_t)row * 8;
  uint4 m0 = *(const uint4*)mp;
  uint4 m1 = *(const uint4*)(mp + 4);
  u32 mw[8] = {m0.x, m0.y, m0.z, m0.w, m1.x, m1.y, m1.z, m1.w};
  if (!(mw[0] | mw[1] | mw[2] | mw[3] | mw[4] | mw[5] | mw[6] | mw[7])) return;
  const float* a = kmat + (size_t)row * DDIM;
  #pragma unroll
  for (int wd = 0; wd < 8; ++wd) {
    u32 m = mw[wd];
    if (!m) continue;
    u32 pk = packed[(size_t)row * 8 + wd];
    while (m) {
      int b = __ffs(m) - 1;  m &= m - 1;
      int s = wd * 32 + b;
      float acc = seq_dot_np(a, gt + (size_t)s * DDIM);
      if (acc > 0.0f) pk |= (1u << b);
      else            pk &= ~(1u << b);
    }
    packed[(size_t)row * 8 + wd] = pk;
  }
}

// ------------------------------------------------------------------
// est = q_sketch @ sign^T, bits -> ±1 f16 on the fly, MFMA f16, f32 out
__launch_bounds__(256)
__global__ void est_kernel(const f16* __restrict__ qs16,
                           const u32* __restrict__ packed,
                           float* __restrict__ out) {
  const int tid  = threadIdx.x;
  const int lane = tid & 63;
  const int w    = tid >> 6;
  const int wg   = blockIdx.x;
  const int head   = wg >> 5;
  const int kchunk = (wg & 31) * 256;
  const int g4 = lane >> 4, ln = lane & 15;

  f16x8 aq[8];
  const f16* qb = qs16 + (size_t)head * 16 * SDIM;
  #pragma unroll
  for (int c = 0; c < 8; ++c)
    aq[c] = *(const f16x8*)(qb + ln * SDIM + c * 32 + g4 * 8);

  const int kb = kchunk + w * 64;
  #pragma unroll
  for (int kt = 0; kt < 4; ++kt) {
    int krow = kb + kt * 16 + ln;
    const u32* bp = packed + (size_t)(head * KLEN + krow) * 8;
    uint4 q0 = *(const uint4*)bp;
    uint4 q1 = *(const uint4*)(bp + 4);
    u32 b32[8] = {q0.x, q0.y, q0.z, q0.w, q1.x, q1.y, q1.z, q1.w};
    f32x4 acc = {0, 0, 0, 0};
    #pragma unroll
    for (int c = 0; c < 8; ++c) {
      u32 byte8 = (b32[c] >> (8 * g4)) & 0xffu;
      union { u32 u[4]; f16x8 h; } sv;
      #pragma unroll
      for (int pp = 0; pp < 4; ++pp) {
        u32 v = 0x3C003C00u;
        v |= ((byte8 >> (2 * pp))     & 1u) ? 0u : 0x8000u;
        v |= ((byte8 >> (2 * pp + 1)) & 1u) ? 0u : 0x80000000u;
        sv.u[pp] = v;
      }
      acc = __builtin_amdgcn_mfma_f32_16x16x32_f16(aq[c], sv.h, acc, 0, 0, 0);
    }
    float* ob = out + (size_t)(head * 16) * KLEN + kb + kt * 16 + ln;
    #pragma unroll
    for (int r = 0; r < 4; ++r) {
      int qrow = g4 * 4 + r;
      ob[(size_t)qrow * KLEN] = acc[r] * SCALE;
    }
  }
}

// ------------------------------------------------------------------
extern "C" void kernel_launch(void* const* d_in, const int* in_sizes, int n_in,
                              void* d_out, int out_size, void* d_ws, size_t ws_size,
                              hipStream_t stream) {
  const float* q = (const float*)d_in[0];
  const float* k = (const float*)d_in[1];
  const float* G = (const float*)d_in[2];
  float* out = (float*)d_out;
  char* ws = (char*)d_ws;

  f16*   qs16   = (f16*)(ws + QS_OFF);
  f16*   gfh    = (f16*)(ws + GFH_OFF);
  f16*   gfl    = (f16*)(ws + GFL_OFF);
  float* gt     = (float*)(ws + GT_OFF);
  u32*   packed = (u32*)(ws + PACKED_OFF);

  // suspect mask in d_out (32MB << 67MB); fully rewritten by proj_sign
  // each call; est overwrites d_out afterwards (stream-ordered).
  u32* smask = (u32*)d_out;

  prep_qs_kernel<<<2048, 256, 0, stream>>>(q, G, qs16);
  prep_g_kernel<<<16, 256, 0, stream>>>(G, gfh, gfl, gt);
  proj_sign_kernel<<<4096, 512, 0, stream>>>(k, gfh, gfl, packed, smask);
  fixup_kernel<<<4096, 256, 0, stream>>>(k, gt, packed, smask);
  est_kernel<<<4096, 256, 0, stream>>>(qs16, packed, out);
}

// Round 23
// 307.928 us; speedup vs baseline: 1.1291x; 1.1291x over previous
//
#include <hip/hip_runtime.h>
#include <math.h>

typedef _Float16 f16;
typedef _Float16 f16x4 __attribute__((ext_vector_type(4)));
typedef _Float16 f16x8 __attribute__((ext_vector_type(8)));
typedef float    f32x4 __attribute__((ext_vector_type(4)));
typedef unsigned int u32;
typedef unsigned long long u64;

#define NHEADS 128
#define KLEN   8192
#define DDIM   128
#define SDIM   256
#define NROWS  (NHEADS * KLEN)       // 1,048,576 k-rows
#define SCALE  1.2533141373155003f   // sqrt(pi/2)
#define TAU    2e-5f                 // suspect threshold (validated rounds 3/7/9)

// ---- workspace layout ----
// [0, 1MiB)            : qs16 f16 [128 heads][16 q][256 s]
// [1MiB, +64KiB)       : Gfh  f16 fragment-ordered hi   [tl16][kc4][lane64][8]
// [+64K, +128K)        : Gfl  f16 fragment-ordered lo*4096
// [+128K, +256K)       : Gt   f32 [256 s][128 d]  (exact, transposed; fixup)
// [2MiB, 2MiB+32MiB)   : packed sign bits, u32[1M rows][8]
// suspect MASK (u32[1M rows][8], 32MB) lives in d_out (dead until est).
#define QS_OFF     0
#define GFH_OFF    (1u << 20)
#define GFL_OFF    ((1u << 20) + (64u << 10))
#define GT_OFF     ((1u << 20) + (128u << 10))
#define PACKED_OFF (2u << 20)

// ------------------------------------------------------------------
// Sequential f32 dot, d-ascending, single-rounding FMA per step —
// bitwise-matches the numpy reference path (validated round 3).
__device__ __forceinline__ float seq_dot_np(const float* __restrict__ a,
                                            const float* __restrict__ gcol) {
  float acc = 0.0f;
  #pragma unroll 8
  for (int d = 0; d < DDIM; ++d)
    acc = __builtin_fmaf(a[d], gcol[d], acc);
  return acc;
}

// ------------------------------------------------------------------
// prep: q_sketch = q @ G  (f32 accumulate, store f16)
__global__ void prep_qs_kernel(const float* __restrict__ q,
                               const float* __restrict__ G,
                               f16* __restrict__ qs16) {
  int idx = blockIdx.x * 256 + threadIdx.x;      // 524288
  int s  = idx & 255;
  int hq = idx >> 8;
  const float* qr = q + (size_t)hq * DDIM;
  float acc = 0.f;
  #pragma unroll 8
  for (int d = 0; d < DDIM; ++d) acc += qr[d] * G[d * SDIM + s];
  qs16[idx] = (f16)acc;
}

// prep: G -> MFMA-fragment-ordered f16 hi/lo + f32 transposed exact copy.
// Fragment (A or B, same formula): lane&15 -> s = tl*16+(lane&15),
// kk = 8*(lane>>4)+j -> d = kc*32 + (lane>>4)*8 + j.
__global__ void prep_g_kernel(const float* __restrict__ G,
                              f16* __restrict__ gfh, f16* __restrict__ gfl,
                              float* __restrict__ gt) {
  int t = blockIdx.x * 256 + threadIdx.x;        // 4096 threads
  int tl   = t >> 8;
  int c    = (t >> 6) & 3;
  int lane = t & 63;
  int s  = tl * 16 + (lane & 15);
  int d0 = c * 32 + (lane >> 4) * 8;
  f16x8 hh, ll;
  #pragma unroll
  for (int j = 0; j < 8; ++j) {
    float g = G[(size_t)(d0 + j) * SDIM + s];
    f16 h = (f16)g;
    hh[j] = h;
    ll[j] = (f16)((g - (float)h) * 4096.0f);
    gt[(size_t)s * DDIM + d0 + j] = g;
  }
  *(f16x8*)(gfh + (size_t)t * 8) = hh;
  *(f16x8*)(gfl + (size_t)t * 8) = ll;
}

// ------------------------------------------------------------------
// Pass A (G-STATIONARY, single-buffer, 2 barriers/tile — the BEST
// measured configuration, 307-312us total, reproduced 3x; all eight
// structural variants regressed): each wave holds G-fragments for its
// 32-s strip in registers (loaded once); k streams through one 8KB LDS
// tile. Block = 512 thr = 8 waves = full 256 s; 16 tiles of 16 rows.
__launch_bounds__(512, 1)
__global__ void proj_sign_kernel(const float* __restrict__ kmat,
                                 const f16* __restrict__ gfh,
                                 const f16* __restrict__ gfl,
                                 u32* __restrict__ packed,
                                 u32* __restrict__ smask) {
  __shared__ __align__(16) f16 lds[2][4][64][8];   // [hilo][kc][lane][8] = 8KB

  const int tid  = threadIdx.x;
  const int lane = tid & 63;
  const int w    = tid >> 6;                     // wave 0..7 = s-strip
  const int g4 = lane >> 4;
  const int ln = lane & 15;
  const size_t rowbase = (size_t)blockIdx.x * 256;

  // ---- G fragments (stationary A-operand) for strip [w*32, w*32+32) ----
  f16x8 Gh[2][4], Gl[2][4];
  #pragma unroll
  for (int mt = 0; mt < 2; ++mt)
    #pragma unroll
    for (int kc = 0; kc < 4; ++kc) {
      size_t o = ((size_t)((w * 2 + mt) * 4 + kc) * 64 + lane) * 8;
      Gh[mt][kc] = *(const f16x8*)(gfh + o);
      Gl[mt][kc] = *(const f16x8*)(gfl + o);
    }

  // ---- staging indices: thread -> (row, d-quad) of the 16x128 k-tile ----
  const int srl = tid >> 5;                      // 0..15 local row
  const int sd0 = (tid & 31) * 4;                // d offset 0..124
  const int skc = sd0 >> 5;
  const int slf = srl | (((sd0 >> 3) & 3) << 4); // fragment lane
  const int sj0 = sd0 & 7;                       // 0 or 4

  float4 rv = *(const float4*)(kmat + (rowbase + srl) * DDIM + sd0);

  for (int t = 0; t < 16; ++t) {
    // convert this tile's quad and write to LDS fragment slots
    f16x4 h4, l4;
    {
      float vv0 = rv.x, vv1 = rv.y, vv2 = rv.z, vv3 = rv.w;
      f16 h;
      h = (f16)vv0; h4[0] = h; l4[0] = (f16)((vv0 - (float)h) * 4096.0f);
      h = (f16)vv1; h4[1] = h; l4[1] = (f16)((vv1 - (float)h) * 4096.0f);
      h = (f16)vv2; h4[2] = h; l4[2] = (f16)((vv2 - (float)h) * 4096.0f);
      h = (f16)vv3; h4[3] = h; l4[3] = (f16)((vv3 - (float)h) * 4096.0f);
    }
    // prefetch next tile early (latency hides under compute below)
    float4 rn;
    if (t < 15)
      rn = *(const float4*)(kmat + (rowbase + (size_t)(t + 1) * 16 + srl) * DDIM + sd0);
    *(f16x4*)&lds[0][skc][slf][sj0] = h4;
    *(f16x4*)&lds[1][skc][slf][sj0] = l4;
    __syncthreads();

    // ---- compute: 24 MFMA (2 m-tiles x 4 kc x 3 chains) ----
    f32x4 ah0 = {0,0,0,0}, aa0 = {0,0,0,0}, ab0 = {0,0,0,0};
    f32x4 ah1 = {0,0,0,0}, aa1 = {0,0,0,0}, ab1 = {0,0,0,0};
    #pragma unroll
    for (int kc = 0; kc < 4; ++kc) {
      f16x8 Bh = *(const f16x8*)&lds[0][kc][lane][0];
      f16x8 Bl = *(const f16x8*)&lds[1][kc][lane][0];
      ah0 = __builtin_amdgcn_mfma_f32_16x16x32_f16(Gh[0][kc], Bh, ah0, 0, 0, 0);
      aa0 = __builtin_amdgcn_mfma_f32_16x16x32_f16(Gh[0][kc], Bl, aa0, 0, 0, 0);
      ab0 = __builtin_amdgcn_mfma_f32_16x16x32_f16(Gl[0][kc], Bh, ab0, 0, 0, 0);
      ah1 = __builtin_amdgcn_mfma_f32_16x16x32_f16(Gh[1][kc], Bh, ah1, 0, 0, 0);
      aa1 = __builtin_amdgcn_mfma_f32_16x16x32_f16(Gh[1][kc], Bl, aa1, 0, 0, 0);
      ab1 = __builtin_amdgcn_mfma_f32_16x16x32_f16(Gl[1][kc], Bh, ab1, 0, 0, 0);
    }
    float p[2][4];
    #pragma unroll
    for (int r = 0; r < 4; ++r) {
      p[0][r] = ah0[r] + (aa0[r] + ab0[r]) * 2.44140625e-4f;   // 1/4096
      p[1][r] = ah1[r] + (aa1[r] + ab1[r]) * 2.44140625e-4f;
    }

    // ---- per-lane bit build: lane owns col (row ln), rows m = g4*4+r ----
    u32 pbits = 0, sbits = 0;
    #pragma unroll
    for (int mt = 0; mt < 2; ++mt)
      #pragma unroll
      for (int r = 0; r < 4; ++r)
        if (p[mt][r] > 0.0f) pbits |= (1u << (mt * 16 + g4 * 4 + r));
    float mn = __builtin_fabsf(p[0][0]);
    #pragma unroll
    for (int mt = 0; mt < 2; ++mt)
      #pragma unroll
      for (int r = 0; r < 4; ++r)
        mn = fminf(mn, __builtin_fabsf(p[mt][r]));
    if (__any(mn < TAU ? 1 : 0)) {
      #pragma unroll
      for (int mt = 0; mt < 2; ++mt)
        #pragma unroll
        for (int r = 0; r < 4; ++r)
          if (__builtin_fabsf(p[mt][r]) < TAU) sbits |= (1u << (mt * 16 + g4 * 4 + r));
    }
    // OR across the 4-lane column group {ln, ln+16, ln+32, ln+48}
    pbits |= __shfl_xor(pbits, 16);  pbits |= __shfl_xor(pbits, 32);
    sbits |= __shfl_xor(sbits, 16);  sbits |= __shfl_xor(sbits, 32);
    if (lane < 16) {
      size_t row = rowbase + (size_t)t * 16 + ln;
      packed[row * 8 + w] = pbits;
      smask [row * 8 + w] = sbits;
    }
    __syncthreads();                             // before overwriting LDS
    if (t < 15) rv = rn;
  }
}

// ------------------------------------------------------------------
// Pass B: one thread per k-row; ~6K suspects total -> mask-scan bound.
__global__ void fixup_kernel(const float* __restrict__ kmat,
                             const float* __restrict__ gt,
                             u32* __restrict__ packed,
                             const u32* __restrict__ smask) {
  int row = blockIdx.x * 256 + threadIdx.x;
  if (row >= NROWS) return;
  const u32* mp = smask + (size_t)row * 8;
  uint4 m0 = *(const uint4*)mp;
  uint4 m1 = *(const uint4*)(mp + 4);
  u32 mw[8] = {m0.x, m0.y, m0.z, m0.w, m1.x, m1.y, m1.z, m1.w};
  if (!(mw[0] | mw[1] | mw[2] | mw[3] | mw[4] | mw[5] | mw[6] | mw[7])) return;
  const float* a = kmat + (size_t)row * DDIM;
  #pragma unroll
  for (int wd = 0; wd < 8; ++wd) {
    u32 m = mw[wd];
    if (!m) continue;
    u32 pk = packed[(size_t)row * 8 + wd];
    while (m) {
      int b = __ffs(m) - 1;  m &= m - 1;
      int s = wd * 32 + b;
      float acc = seq_dot_np(a, gt + (size_t)s * DDIM);
      if (acc > 0.0f) pk |= (1u << b);
      else            pk &= ~(1u << b);
    }
    packed[(size_t)row * 8 + wd] = pk;
  }
}

// ------------------------------------------------------------------
// est = q_sketch @ sign^T, bits -> ±1 f16 on the fly, MFMA f16, f32 out
__launch_bounds__(256)
__global__ void est_kernel(const f16* __restrict__ qs16,
                           const u32* __restrict__ packed,
                           float* __restrict__ out) {
  const int tid  = threadIdx.x;
  const int lane = tid & 63;
  const int w    = tid >> 6;
  const int wg   = blockIdx.x;
  const int head   = wg >> 5;
  const int kchunk = (wg & 31) * 256;
  const int g4 = lane >> 4, ln = lane & 15;

  f16x8 aq[8];
  const f16* qb = qs16 + (size_t)head * 16 * SDIM;
  #pragma unroll
  for (int c = 0; c < 8; ++c)
    aq[c] = *(const f16x8*)(qb + ln * SDIM + c * 32 + g4 * 8);

  const int kb = kchunk + w * 64;
  #pragma unroll
  for (int kt = 0; kt < 4; ++kt) {
    int krow = kb + kt * 16 + ln;
    const u32* bp = packed + (size_t)(head * KLEN + krow) * 8;
    uint4 q0 = *(const uint4*)bp;
    uint4 q1 = *(const uint4*)(bp + 4);
    u32 b32[8] = {q0.x, q0.y, q0.z, q0.w, q1.x, q1.y, q1.z, q1.w};
    f32x4 acc = {0, 0, 0, 0};
    #pragma unroll
    for (int c = 0; c < 8; ++c) {
      u32 byte8 = (b32[c] >> (8 * g4)) & 0xffu;
      union { u32 u[4]; f16x8 h; } sv;
      #pragma unroll
      for (int pp = 0; pp < 4; ++pp) {
        u32 v = 0x3C003C00u;
        v |= ((byte8 >> (2 * pp))     & 1u) ? 0u : 0x8000u;
        v |= ((byte8 >> (2 * pp + 1)) & 1u) ? 0u : 0x80000000u;
        sv.u[pp] = v;
      }
      acc = __builtin_amdgcn_mfma_f32_16x16x32_f16(aq[c], sv.h, acc, 0, 0, 0);
    }
    float* ob = out + (size_t)(head * 16) * KLEN + kb + kt * 16 + ln;
    #pragma unroll
    for (int r = 0; r < 4; ++r) {
      int qrow = g4 * 4 + r;
      ob[(size_t)qrow * KLEN] = acc[r] * SCALE;
    }
  }
}

// ------------------------------------------------------------------
extern "C" void kernel_launch(void* const* d_in, const int* in_sizes, int n_in,
                              void* d_out, int out_size, void* d_ws, size_t ws_size,
                              hipStream_t stream) {
  const float* q = (const float*)d_in[0];
  const float* k = (const float*)d_in[1];
  const float* G = (const float*)d_in[2];
  float* out = (float*)d_out;
  char* ws = (char*)d_ws;

  f16*   qs16   = (f16*)(ws + QS_OFF);
  f16*   gfh    = (f16*)(ws + GFH_OFF);
  f16*   gfl    = (f16*)(ws + GFL_OFF);
  float* gt     = (float*)(ws + GT_OFF);
  u32*   packed = (u32*)(ws + PACKED_OFF);

  // suspect mask in d_out (32MB << 67MB); fully rewritten by proj_sign
  // each call; est overwrites d_out afterwards (stream-ordered).
  u32* smask = (u32*)d_out;

  prep_qs_kernel<<<2048, 256, 0, stream>>>(q, G, qs16);
  prep_g_kernel<<<16, 256, 0, stream>>>(G, gfh, gfl, gt);
  proj_sign_kernel<<<4096, 512, 0, stream>>>(k, gfh, gfl, packed, smask);
  fixup_kernel<<<4096, 256, 0, stream>>>(k, gt, packed, smask);
  est_kernel<<<4096, 256, 0, stream>>>(qs16, packed, out);
}